// Round 3
// baseline (4063.975 us; speedup 1.0000x reference)
//
#include <hip/hip_runtime.h>

#define D_DIM 256
#define K_CODES 1024

// async global->LDS, 16B per lane; LDS dest = wave-uniform base + lane*16
__device__ __forceinline__ void gload16(const float* g, float4* l) {
    __builtin_amdgcn_global_load_lds(
        (const __attribute__((address_space(1))) void*)g,
        (__attribute__((address_space(3))) void*)l, 16, 0, 0);
}

// ---------------------------------------------------------------------------
// Fused prep: blocks [0,128) z2 | [128,132) e2 | [132,388) ET transpose |
//             [388,420) rowKey init (+lossAcc zero)
// NUMERICS: e2 chain (float4 x,y,z,w ascending) must stay bit-identical —
// it discriminates codes. z2 order is argmin-invariant (uniform grid shift)
// but kept as the validated ascending-d chain anyway.
// ---------------------------------------------------------------------------
__global__ __launch_bounds__(256) void k_prep(const float* __restrict__ z,
                                              const float* __restrict__ e,
                                              float* __restrict__ z2,
                                              float* __restrict__ e2,
                                              float* __restrict__ et,
                                              unsigned long long* __restrict__ rowKey,
                                              float* __restrict__ lossAcc) {
    __shared__ float tile[32][33];
    const int bi = blockIdx.x;
    const int t  = threadIdx.x;
    if (bi < 128) {                    // ---- z2 ----
        int n = bi * 256 + t;
        int b = n >> 10, nl = n & 1023;
        const float* p = z + (size_t)b * (D_DIM * 1024) + nl;
        float s = 0.f;
#pragma unroll 8
        for (int d = 0; d < D_DIM; ++d) {
            float v = p[(size_t)d * 1024];
            s = fmaf(v, v, s);
        }
        z2[n] = s;
    } else if (bi < 132) {             // ---- e2 ----
        int k = (bi - 128) * 256 + t;
        const float4* p = (const float4*)(e + (size_t)k * D_DIM);
        float s = 0.f;
#pragma unroll 4
        for (int c = 0; c < D_DIM / 4; ++c) {
            float4 v = p[c];
            s = fmaf(v.x, v.x, s); s = fmaf(v.y, v.y, s);
            s = fmaf(v.z, v.z, s); s = fmaf(v.w, v.w, s);
        }
        e2[k] = s;
    } else if (bi < 388) {             // ---- ET[d][k] = E[k][d] ----
        int bb = bi - 132;
        const int k0 = (bb & 31) * 32;
        const int d0 = (bb >> 5) * 32;
        {
            int kk = t >> 3, c4 = (t & 7) * 4;
            float4 v = *(const float4*)(e + (size_t)(k0 + kk) * D_DIM + d0 + c4);
            tile[c4 + 0][kk] = v.x; tile[c4 + 1][kk] = v.y;
            tile[c4 + 2][kk] = v.z; tile[c4 + 3][kk] = v.w;
        }
        __syncthreads();
        {
            int dd = t >> 3, kc4 = (t & 7) * 4;
            float4 o;
            o.x = tile[dd][kc4 + 0]; o.y = tile[dd][kc4 + 1];
            o.z = tile[dd][kc4 + 2]; o.w = tile[dd][kc4 + 3];
            *(float4*)(et + (size_t)(d0 + dd) * K_CODES + k0 + kc4) = o;
        }
    } else {                           // ---- rowKey init ----
        int bb = bi - 388;             // 0..31, 1024 u64 each
        if (bb == 0 && t == 0) lossAcc[0] = 0.f;
#pragma unroll
        for (int j = 0; j < 4; ++j)
            rowKey[bb * 1024 + j * 256 + t] = 0xFFFFFFFFFFFFFFFFULL;
    }
}

// ---------------------------------------------------------------------------
// Main: 128 rows x 128 codes per block, K split 8x (grid 2048, all resident:
// 8 blocks/CU at 16 KB LDS). Double-buffered slab=8 pipeline via
// global_load_lds; E tile XOR-swizzled (slot j holds element j^(j>>3)) so
// reads hit 2 lanes/bank-quad (free). Thread tile 8x8.
// NUMERICS: per (n,k) ze is a single ascending-d fp32 FMA chain, then
// dist = fmaf(-2, ze, fl(z2+e2)) — bit-identical to rounds 1/2 (validated).
// ---------------------------------------------------------------------------
__global__ __launch_bounds__(256, 8) void k_main(const float* __restrict__ z,
                                                 const float* __restrict__ et,
                                                 const float* __restrict__ z2,
                                                 const float* __restrict__ e2,
                                                 unsigned long long* __restrict__ rowKey) {
    __shared__ float4 lds4[1024];   // [buf:2][Z:256 | E:256] float4 = 16 KB

    const int t    = threadIdx.x;
    const int lane = t & 63;
    const int w    = t >> 6;        // wave 0..3
    const int tk   = t & 15;        // code group
    const int tr   = t >> 4;        // row group 0..15
    const int kc   = blockIdx.x & 7;
    const int rb   = blockIdx.x >> 3;
    const int n0   = rb * 128;
    const int b    = n0 >> 10;
    const int nl0  = n0 & 1023;
    const int k0   = kc * 128;

    // staging sources (per-lane): slot (w*64+lane) -> row dd, col c4
    const int c4   = lane & 31;
    const int sw   = c4 ^ (c4 >> 3);            // involutive float4 swizzle
    const int ddw  = w * 2 + (lane >> 5);       // 0..7 within slab
    const float* zs = z  + (size_t)b * (D_DIM * 1024) + nl0
                         + (size_t)ddw * 1024 + c4 * 4;
    const float* es = et + (size_t)ddw * K_CODES + k0 + sw * 4;

    // reader E slots: element 2tk lives at slot swz(2tk) = 2tk ^ (tk>>2)
    const int e0 = (2 * tk) ^ (tk >> 2);
    const int e1 = e0 ^ 1;

    float acc[8][8];
#pragma unroll
    for (int i = 0; i < 8; ++i)
#pragma unroll
        for (int j = 0; j < 8; ++j) acc[i][j] = 0.f;

    // prologue: stage slab 0 into buf 0
    gload16(zs, &lds4[w * 64]);
    gload16(es, &lds4[256 + w * 64]);
    zs += 8192; es += 8192;                     // next slab (d0 += 8)
    __syncthreads();

    for (int s = 0; s < 32; ++s) {
        const int cb = (s & 1) * 512;           // current buffer base
        const int nb = 512 - cb;                // next buffer base
        if (s < 31) {
            gload16(zs, &lds4[nb + w * 64]);
            gload16(es, &lds4[nb + 256 + w * 64]);
            zs += 8192; es += 8192;
        }
        const float4* Zb = &lds4[cb];
        const float4* Eb = &lds4[cb + 256];
#pragma unroll
        for (int dd = 0; dd < 8; ++dd) {
            float4 za = Zb[dd * 32 + tr * 2];
            float4 zc = Zb[dd * 32 + tr * 2 + 1];
            float4 ea = Eb[dd * 32 + e0];
            float4 eb = Eb[dd * 32 + e1];
            float zz[8] = { za.x, za.y, za.z, za.w, zc.x, zc.y, zc.z, zc.w };
            float ee[8] = { ea.x, ea.y, ea.z, ea.w, eb.x, eb.y, eb.z, eb.w };
#pragma unroll
            for (int i = 0; i < 8; ++i)
#pragma unroll
                for (int j = 0; j < 8; ++j)
                    acc[i][j] = fmaf(zz[i], ee[j], acc[i][j]);
        }
        __syncthreads();
    }

    // dist + within-thread argmin (ascending k => first-min tiebreak)
    float z2r[8], e2r[8];
#pragma unroll
    for (int i = 0; i < 8; ++i) z2r[i] = z2[n0 + tr * 8 + i];
#pragma unroll
    for (int j = 0; j < 8; ++j) e2r[j] = e2[k0 + tk * 8 + j];

    unsigned long long bKey[8];
#pragma unroll
    for (int i = 0; i < 8; ++i) bKey[i] = 0xFFFFFFFFFFFFFFFFULL;
#pragma unroll
    for (int i = 0; i < 8; ++i) {
#pragma unroll
        for (int j = 0; j < 8; ++j) {
            float t1 = z2r[i] + e2r[j];              // fl(z2 + e2)
            float dist = fmaf(-2.0f, acc[i][j], t1); // fl(t1 - 2*ze)
            unsigned long long key =
                ((unsigned long long)__float_as_uint(dist) << 32) |
                (unsigned int)(k0 + tk * 8 + j);
            if (key < bKey[i]) bKey[i] = key;
        }
    }
#pragma unroll
    for (int m = 1; m < 16; m <<= 1) {
#pragma unroll
        for (int i = 0; i < 8; ++i) {
            unsigned long long o = __shfl_xor(bKey[i], m, 64);
            if (o < bKey[i]) bKey[i] = o;
        }
    }
    if (tk == 0) {
#pragma unroll
        for (int i = 0; i < 8; ++i)
            atomicMin(&rowKey[n0 + tr * 8 + i], bKey[i]);
    }
}

// ---------------------------------------------------------------------------
// Epilogue: resolve idx from rowKey + z_q gather + straight-through out +
// loss partial sums. 64 rows x 256 d per block.
// ---------------------------------------------------------------------------
__global__ __launch_bounds__(256) void k_epilogue(const float* __restrict__ z,
                                                  const float* __restrict__ e,
                                                  const unsigned long long* __restrict__ rowKey,
                                                  float* __restrict__ outZ,
                                                  float* __restrict__ outIdx,
                                                  float* __restrict__ lossAcc) {
    __shared__ float4 zq4[64][64];
    __shared__ int idxs[64];
    const int t = threadIdx.x;
    const int n0 = blockIdx.x * 64;
    const int b = n0 >> 10, nl0 = n0 & 1023;

    if (t < 64) {
        unsigned long long key = rowKey[n0 + t];
        int bi = (int)(unsigned int)(key & 0xFFFFFFFFULL);
        idxs[t] = bi;
        outIdx[n0 + t] = (float)bi;
    }
    __syncthreads();

#pragma unroll
    for (int j = 0; j < 16; ++j) {
        int flat = j * 256 + t;
        int i  = flat >> 6;
        int c4 = flat & 63;
        float4 v = *(const float4*)(e + (size_t)idxs[i] * D_DIM + c4 * 4);
        zq4[i][c4 ^ (i & 7)] = v;
    }
    __syncthreads();

    const int i  = t & 63;
    const int dg = t >> 6;
    const float* zp = z    + (size_t)b * (D_DIM * 1024) + nl0 + i;
    float*       op = outZ + (size_t)b * (D_DIM * 1024) + nl0 + i;
    float s = 0.f;
#pragma unroll 4
    for (int c = 0; c < 16; ++c) {
        int c4 = dg * 16 + c;
        float4 q = zq4[i][c4 ^ (i & 7)];
        int d = c4 * 4;
        float zv, df;
        zv = zp[(size_t)(d + 0) * 1024]; df = q.x - zv; s = fmaf(df, df, s); op[(size_t)(d + 0) * 1024] = zv + df;
        zv = zp[(size_t)(d + 1) * 1024]; df = q.y - zv; s = fmaf(df, df, s); op[(size_t)(d + 1) * 1024] = zv + df;
        zv = zp[(size_t)(d + 2) * 1024]; df = q.z - zv; s = fmaf(df, df, s); op[(size_t)(d + 2) * 1024] = zv + df;
        zv = zp[(size_t)(d + 3) * 1024]; df = q.w - zv; s = fmaf(df, df, s); op[(size_t)(d + 3) * 1024] = zv + df;
    }
#pragma unroll
    for (int off = 32; off > 0; off >>= 1) s += __shfl_down(s, off, 64);
    if ((t & 63) == 0) atomicAdd(lossAcc, s);
}

__global__ void k_final(const float* __restrict__ lossAcc,
                        float* __restrict__ outLoss) {
    float m = lossAcc[0] * (1.0f / 8388608.0f);
    outLoss[0] = m + 0.25f * m;
}

// ---------------------------------------------------------------------------
extern "C" void kernel_launch(void* const* d_in, const int* in_sizes, int n_in,
                              void* d_out, int out_size, void* d_ws, size_t ws_size,
                              hipStream_t stream) {
    const float* z = (const float*)d_in[0];   // (32,256,32,32)
    const float* e = (const float*)d_in[1];   // (1024,256)
    float* out     = (float*)d_out;
    float* outIdx  = out + 8388608;
    float* outLoss = out + 8421376;

    float* z2      = (float*)d_ws;                         // 32768 f
    float* e2      = z2 + 32768;                           // 1024 f
    float* lossAcc = e2 + 1024;                            // 1 f
    uintptr_t p = (uintptr_t)(lossAcc + 1);
    p = (p + 255) & ~(uintptr_t)255;
    unsigned long long* rowKey = (unsigned long long*)p;   // 32768 u64
    float* et = (float*)(rowKey + 32768);                  // 262144 f

    k_prep<<<420, 256, 0, stream>>>(z, e, z2, e2, et, rowKey, lossAcc);
    k_main<<<2048, 256, 0, stream>>>(z, et, z2, e2, rowKey);
    k_epilogue<<<512, 256, 0, stream>>>(z, e, rowKey, out, outIdx, lossAcc);
    k_final<<<1, 1, 0, stream>>>(lossAcc, outLoss);
}

// Round 4
// 268.494 us; speedup vs baseline: 15.1362x; 15.1362x over previous
//
#include <hip/hip_runtime.h>

#define D_DIM 256
#define K_CODES 1024

// async global->LDS, 16B per lane; LDS dest = wave-uniform base + lane*16
__device__ __forceinline__ void gload16(const float* g, float4* l) {
    __builtin_amdgcn_global_load_lds(
        (const __attribute__((address_space(1))) void*)g,
        (__attribute__((address_space(3))) void*)l, 16, 0, 0);
}

// ---------------------------------------------------------------------------
// Fused prep: blocks [0,128) z2 | [128,132) e2 | [132,388) ET transpose |
//             [388,420) rowKey init (+lossAcc zero)
// NUMERICS: e2 chain (float4 x,y,z,w ascending) must stay bit-identical —
// it discriminates codes. z2 kept as the validated ascending-d chain.
// ---------------------------------------------------------------------------
__global__ __launch_bounds__(256) void k_prep(const float* __restrict__ z,
                                              const float* __restrict__ e,
                                              float* __restrict__ z2,
                                              float* __restrict__ e2,
                                              float* __restrict__ et,
                                              unsigned long long* __restrict__ rowKey,
                                              float* __restrict__ lossAcc) {
    __shared__ float tile[32][33];
    const int bi = blockIdx.x;
    const int t  = threadIdx.x;
    if (bi < 128) {                    // ---- z2 ----
        int n = bi * 256 + t;
        int b = n >> 10, nl = n & 1023;
        const float* p = z + (size_t)b * (D_DIM * 1024) + nl;
        float s = 0.f;
#pragma unroll 8
        for (int d = 0; d < D_DIM; ++d) {
            float v = p[(size_t)d * 1024];
            s = fmaf(v, v, s);
        }
        z2[n] = s;
    } else if (bi < 132) {             // ---- e2 ----
        int k = (bi - 128) * 256 + t;
        const float4* p = (const float4*)(e + (size_t)k * D_DIM);
        float s = 0.f;
#pragma unroll 4
        for (int c = 0; c < D_DIM / 4; ++c) {
            float4 v = p[c];
            s = fmaf(v.x, v.x, s); s = fmaf(v.y, v.y, s);
            s = fmaf(v.z, v.z, s); s = fmaf(v.w, v.w, s);
        }
        e2[k] = s;
    } else if (bi < 388) {             // ---- ET[d][k] = E[k][d] ----
        int bb = bi - 132;
        const int k0 = (bb & 31) * 32;
        const int d0 = (bb >> 5) * 32;
        {
            int kk = t >> 3, c4 = (t & 7) * 4;
            float4 v = *(const float4*)(e + (size_t)(k0 + kk) * D_DIM + d0 + c4);
            tile[c4 + 0][kk] = v.x; tile[c4 + 1][kk] = v.y;
            tile[c4 + 2][kk] = v.z; tile[c4 + 3][kk] = v.w;
        }
        __syncthreads();
        {
            int dd = t >> 3, kc4 = (t & 7) * 4;
            float4 o;
            o.x = tile[dd][kc4 + 0]; o.y = tile[dd][kc4 + 1];
            o.z = tile[dd][kc4 + 2]; o.w = tile[dd][kc4 + 3];
            *(float4*)(et + (size_t)(d0 + dd) * K_CODES + k0 + kc4) = o;
        }
    } else {                           // ---- rowKey init ----
        int bb = bi - 388;             // 0..31, 1024 u64 each
        if (bb == 0 && t == 0) lossAcc[0] = 0.f;
#pragma unroll
        for (int j = 0; j < 4; ++j)
            rowKey[bb * 1024 + j * 256 + t] = 0xFFFFFFFFFFFFFFFFULL;
    }
}

// ---------------------------------------------------------------------------
// Main: 128 rows x 128 codes per block, K split 8x (grid 2048). Double-
// buffered slab=8 pipeline via global_load_lds; E tile XOR-swizzled (slot j
// holds element j^(j>>3)): E reads = 2 addrs/bank-group (free), Z reads =
// broadcast. Thread tile 8x8.
// launch_bounds(256,4): VGPR budget 128 >= ~92 live. (256,8) in round 3
// capped VGPRs at 32 -> acc spilled to scratch -> 20 GB traffic, 19x slower.
// NUMERICS: per (n,k) ze is a single ascending-d fp32 FMA chain, then
// dist = fmaf(-2, ze, fl(z2+e2)) — bit-identical to rounds 1/2 (validated).
// ---------------------------------------------------------------------------
__global__ __launch_bounds__(256, 4) void k_main(const float* __restrict__ z,
                                                 const float* __restrict__ et,
                                                 const float* __restrict__ z2,
                                                 const float* __restrict__ e2,
                                                 unsigned long long* __restrict__ rowKey) {
    __shared__ float4 lds4[1024];   // [buf:2][Z:256 | E:256] float4 = 16 KB

    const int t    = threadIdx.x;
    const int lane = t & 63;
    const int w    = t >> 6;        // wave 0..3
    const int tk   = t & 15;        // code group
    const int tr   = t >> 4;        // row group 0..15
    const int kc   = blockIdx.x & 7;
    const int rb   = blockIdx.x >> 3;
    const int n0   = rb * 128;
    const int b    = n0 >> 10;
    const int nl0  = n0 & 1023;
    const int k0   = kc * 128;

    // staging sources (per-lane): slot (w*64+lane) -> row dd, col c4
    const int c4   = lane & 31;
    const int sw   = c4 ^ (c4 >> 3);            // involutive float4 swizzle
    const int ddw  = w * 2 + (lane >> 5);       // 0..7 within slab
    const float* zs = z  + (size_t)b * (D_DIM * 1024) + nl0
                         + (size_t)ddw * 1024 + c4 * 4;
    const float* es = et + (size_t)ddw * K_CODES + k0 + sw * 4;

    // reader E slots: element 2tk lives at slot swz(2tk) = 2tk ^ (tk>>2)
    const int e0 = (2 * tk) ^ (tk >> 2);
    const int e1 = e0 ^ 1;

    float acc[8][8];
#pragma unroll
    for (int i = 0; i < 8; ++i)
#pragma unroll
        for (int j = 0; j < 8; ++j) acc[i][j] = 0.f;

    // prologue: stage slab 0 into buf 0
    gload16(zs, &lds4[w * 64]);
    gload16(es, &lds4[256 + w * 64]);
    zs += 8192; es += 8192;                     // next slab (d0 += 8)
    __syncthreads();

    for (int s = 0; s < 32; ++s) {
        const int cb = (s & 1) * 512;           // current buffer base
        const int nb = 512 - cb;                // next buffer base
        if (s < 31) {
            gload16(zs, &lds4[nb + w * 64]);
            gload16(es, &lds4[nb + 256 + w * 64]);
            zs += 8192; es += 8192;
        }
        const float4* Zb = &lds4[cb];
        const float4* Eb = &lds4[cb + 256];
#pragma unroll
        for (int dd = 0; dd < 8; ++dd) {
            float4 za = Zb[dd * 32 + tr * 2];
            float4 zc = Zb[dd * 32 + tr * 2 + 1];
            float4 ea = Eb[dd * 32 + e0];
            float4 eb = Eb[dd * 32 + e1];
            float zz[8] = { za.x, za.y, za.z, za.w, zc.x, zc.y, zc.z, zc.w };
            float ee[8] = { ea.x, ea.y, ea.z, ea.w, eb.x, eb.y, eb.z, eb.w };
#pragma unroll
            for (int i = 0; i < 8; ++i)
#pragma unroll
                for (int j = 0; j < 8; ++j)
                    acc[i][j] = fmaf(zz[i], ee[j], acc[i][j]);
        }
        __syncthreads();
    }

    // dist + within-thread argmin (ascending k => first-min tiebreak)
    float z2r[8], e2r[8];
#pragma unroll
    for (int i = 0; i < 8; ++i) z2r[i] = z2[n0 + tr * 8 + i];
#pragma unroll
    for (int j = 0; j < 8; ++j) e2r[j] = e2[k0 + tk * 8 + j];

    unsigned long long bKey[8];
#pragma unroll
    for (int i = 0; i < 8; ++i) bKey[i] = 0xFFFFFFFFFFFFFFFFULL;
#pragma unroll
    for (int i = 0; i < 8; ++i) {
#pragma unroll
        for (int j = 0; j < 8; ++j) {
            float t1 = z2r[i] + e2r[j];              // fl(z2 + e2)
            float dist = fmaf(-2.0f, acc[i][j], t1); // fl(t1 - 2*ze)
            unsigned long long key =
                ((unsigned long long)__float_as_uint(dist) << 32) |
                (unsigned int)(k0 + tk * 8 + j);
            if (key < bKey[i]) bKey[i] = key;
        }
    }
#pragma unroll
    for (int m = 1; m < 16; m <<= 1) {
#pragma unroll
        for (int i = 0; i < 8; ++i) {
            unsigned long long o = __shfl_xor(bKey[i], m, 64);
            if (o < bKey[i]) bKey[i] = o;
        }
    }
    if (tk == 0) {
#pragma unroll
        for (int i = 0; i < 8; ++i)
            atomicMin(&rowKey[n0 + tr * 8 + i], bKey[i]);
    }
}

// ---------------------------------------------------------------------------
// Epilogue: resolve idx from rowKey + z_q gather + straight-through out +
// loss partial sums. 64 rows x 256 d per block.
// ---------------------------------------------------------------------------
__global__ __launch_bounds__(256) void k_epilogue(const float* __restrict__ z,
                                                  const float* __restrict__ e,
                                                  const unsigned long long* __restrict__ rowKey,
                                                  float* __restrict__ outZ,
                                                  float* __restrict__ outIdx,
                                                  float* __restrict__ lossAcc) {
    __shared__ float4 zq4[64][64];
    __shared__ int idxs[64];
    const int t = threadIdx.x;
    const int n0 = blockIdx.x * 64;
    const int b = n0 >> 10, nl0 = n0 & 1023;

    if (t < 64) {
        unsigned long long key = rowKey[n0 + t];
        int bi = (int)(unsigned int)(key & 0xFFFFFFFFULL);
        idxs[t] = bi;
        outIdx[n0 + t] = (float)bi;
    }
    __syncthreads();

#pragma unroll
    for (int j = 0; j < 16; ++j) {
        int flat = j * 256 + t;
        int i  = flat >> 6;
        int c4 = flat & 63;
        float4 v = *(const float4*)(e + (size_t)idxs[i] * D_DIM + c4 * 4);
        zq4[i][c4 ^ (i & 7)] = v;
    }
    __syncthreads();

    const int i  = t & 63;
    const int dg = t >> 6;
    const float* zp = z    + (size_t)b * (D_DIM * 1024) + nl0 + i;
    float*       op = outZ + (size_t)b * (D_DIM * 1024) + nl0 + i;
    float s = 0.f;
#pragma unroll 4
    for (int c = 0; c < 16; ++c) {
        int c4 = dg * 16 + c;
        float4 q = zq4[i][c4 ^ (i & 7)];
        int d = c4 * 4;
        float zv, df;
        zv = zp[(size_t)(d + 0) * 1024]; df = q.x - zv; s = fmaf(df, df, s); op[(size_t)(d + 0) * 1024] = zv + df;
        zv = zp[(size_t)(d + 1) * 1024]; df = q.y - zv; s = fmaf(df, df, s); op[(size_t)(d + 1) * 1024] = zv + df;
        zv = zp[(size_t)(d + 2) * 1024]; df = q.z - zv; s = fmaf(df, df, s); op[(size_t)(d + 2) * 1024] = zv + df;
        zv = zp[(size_t)(d + 3) * 1024]; df = q.w - zv; s = fmaf(df, df, s); op[(size_t)(d + 3) * 1024] = zv + df;
    }
#pragma unroll
    for (int off = 32; off > 0; off >>= 1) s += __shfl_down(s, off, 64);
    if ((t & 63) == 0) atomicAdd(lossAcc, s);
}

__global__ void k_final(const float* __restrict__ lossAcc,
                        float* __restrict__ outLoss) {
    float m = lossAcc[0] * (1.0f / 8388608.0f);
    outLoss[0] = m + 0.25f * m;
}

// ---------------------------------------------------------------------------
extern "C" void kernel_launch(void* const* d_in, const int* in_sizes, int n_in,
                              void* d_out, int out_size, void* d_ws, size_t ws_size,
                              hipStream_t stream) {
    const float* z = (const float*)d_in[0];   // (32,256,32,32)
    const float* e = (const float*)d_in[1];   // (1024,256)
    float* out     = (float*)d_out;
    float* outIdx  = out + 8388608;
    float* outLoss = out + 8421376;

    float* z2      = (float*)d_ws;                         // 32768 f
    float* e2      = z2 + 32768;                           // 1024 f
    float* lossAcc = e2 + 1024;                            // 1 f
    uintptr_t p = (uintptr_t)(lossAcc + 1);
    p = (p + 255) & ~(uintptr_t)255;
    unsigned long long* rowKey = (unsigned long long*)p;   // 32768 u64
    float* et = (float*)(rowKey + 32768);                  // 262144 f

    k_prep<<<420, 256, 0, stream>>>(z, e, z2, e2, et, rowKey, lossAcc);
    k_main<<<2048, 256, 0, stream>>>(z, et, z2, e2, rowKey);
    k_epilogue<<<512, 256, 0, stream>>>(z, e, rowKey, out, outIdx, lossAcc);
    k_final<<<1, 1, 0, stream>>>(lossAcc, outLoss);
}